// Round 20
// baseline (237.725 us; speedup 1.0000x reference)
//
#include <hip/hip_runtime.h>
#include <math.h>

// ---------------------------------------------------------------------------
// GatedCrossAttention: B=2, NQ=NK=1024, QD=KVD=OD=1024, H=8, DH=64, INNER=512
// Round 20: fc1/fc2 -> 128x64 8-wave tiles (LDS 36KB ring-3 -> 4 blocks/CU =
// 32 waves/CU, the CU max). Delivery ~ resident waves (1.3 GB/s/wave constant
// across r13-r17): 16->32 waves/CU should take both ~50us dispatches to ~37.
// Staging: all 512 threads stage A, threads 0-255 stage W; per-wave vmcnt via
// wave-uniform branch (0-3: vmcnt(2), 4-7: vmcnt(1)). Rest = round 19.
// ---------------------------------------------------------------------------

#define M_ROWS 2048   // B*NQ
#define SEQ    1024

typedef unsigned short u16;
typedef __attribute__((ext_vector_type(8))) short short8;
typedef __attribute__((ext_vector_type(4))) float f32x4;

__device__ inline u16 f2b(float f) {
    unsigned u = __builtin_bit_cast(unsigned, f);
    u += 0x7FFFu + ((u >> 16) & 1u);   // round-to-nearest-even
    return (u16)(u >> 16);
}
__device__ inline float b2f(u16 h) {
    return __builtin_bit_cast(float, (unsigned)h << 16);
}
__device__ inline unsigned cvtpk_bf16(float lo, float hi) {
    unsigned r;
    asm volatile("v_cvt_pk_bf16_f32 %0, %1, %2" : "=v"(r) : "v"(lo), "v"(hi));
    return r;
}

__device__ inline void gload16(const u16* g, u16* l) {
    __builtin_amdgcn_global_load_lds(
        (const __attribute__((address_space(1))) void*)g,
        (__attribute__((address_space(3))) void*)l, 16, 0, 0);
}

// swizzled LDS address (elem units): physical row prow of 32 elems, 8-elem
// chunk index, XOR on (prow>>1)&3  [GEMM-verified conflict-free pattern]
__device__ __forceinline__ int aswz(int prow, int chunk) {
    return prow * 32 + ((chunk ^ ((prow >> 1) & 3)) << 3);
}

// ------------------- fused f32 -> bf16 weight convert -----------------------
struct CvtPack { const float* s[8]; u16* d[8]; };

__global__ __launch_bounds__(256)
void cvt8_kernel(CvtPack p)
{
    constexpr int pre[9] = {0, 1536, 2048, 3072, 3840, 4096, 4608, 8704, 12800};
    const int b = blockIdx.x;
    int seg = 0;
    #pragma unroll
    for (int i = 1; i < 8; ++i) seg += (b >= pre[i]);
    const int off = (b - pre[seg]) * 1024 + threadIdx.x * 4;
    const float4 v = *reinterpret_cast<const float4*>(p.s[seg] + off);
    ushort4 o;
    o.x = f2b(v.x); o.y = f2b(v.y); o.z = f2b(v.z); o.w = f2b(v.w);
    *reinterpret_cast<ushort4*>(p.d[seg] + off) = o;
}

// --------------------------- dual LayerNorm --------------------------------
__global__ __launch_bounds__(256)
void ln_dual(const float* __restrict__ x0, const float* __restrict__ w0,
             const float* __restrict__ b0, u16* __restrict__ out0,
             const float* __restrict__ x1, const float* __restrict__ w1,
             const float* __restrict__ b1, u16* __restrict__ out1, int D)
{
    const int r = blockIdx.x;
    const int sel = r >= M_ROWS;
    const size_t row = sel ? r - M_ROWS : r;
    const float* x = sel ? x1 : x0;
    const float* w = sel ? w1 : w0;
    const float* bias = sel ? b1 : b0;
    u16* out = sel ? out1 : out0;
    const float* xr = x + row * (size_t)D;
    const int c = threadIdx.x * 4;
    float4 v = make_float4(0.f, 0.f, 0.f, 0.f);
    if (c < D) v = *reinterpret_cast<const float4*>(&xr[c]);
    float sum = v.x + v.y + v.z + v.w;
    float sq  = v.x*v.x + v.y*v.y + v.z*v.z + v.w*v.w;
    #pragma unroll
    for (int off = 32; off > 0; off >>= 1) {
        sum += __shfl_down(sum, off);
        sq  += __shfl_down(sq,  off);
    }
    __shared__ float s1[4], s2[4];
    const int wid = threadIdx.x >> 6;
    if ((threadIdx.x & 63) == 0) { s1[wid] = sum; s2[wid] = sq; }
    __syncthreads();
    const float tsum = s1[0] + s1[1] + s1[2] + s1[3];
    const float tsq  = s2[0] + s2[1] + s2[2] + s2[3];
    const float mean = tsum / (float)D;
    const float var  = tsq / (float)D - mean * mean;
    const float rstd = rsqrtf(var + 1e-5f);
    if (c < D) {
        ushort4 o;
        o.x = f2b((v.x - mean) * rstd * w[c+0] + bias[c+0]);
        o.y = f2b((v.y - mean) * rstd * w[c+1] + bias[c+1]);
        o.z = f2b((v.z - mean) * rstd * w[c+2] + bias[c+2]);
        o.w = f2b((v.w - mean) * rstd * w[c+3] + bias[c+3]);
        *reinterpret_cast<ushort4*>(&out[row * (size_t)D + c]) = o;
    }
}

// ---- fused split-K reduce + LayerNorm: delta = p0+p1 (write f32) + LN -----
__global__ __launch_bounds__(256)
void ln_sum(const float* __restrict__ p, float* __restrict__ dout,
            const float* __restrict__ w, const float* __restrict__ bias,
            u16* __restrict__ out)
{
    const size_t row = blockIdx.x;
    const int c = threadIdx.x * 4;
    const float* r0 = p + row * 1024 + c;
    const float* r1 = r0 + 2097152;          // plane 1
    const float4 a = *reinterpret_cast<const float4*>(r0);
    const float4 b = *reinterpret_cast<const float4*>(r1);
    float4 v;
    v.x = a.x + b.x; v.y = a.y + b.y; v.z = a.z + b.z; v.w = a.w + b.w;
    *reinterpret_cast<float4*>(&dout[row * 1024 + c]) = v;

    float sum = v.x + v.y + v.z + v.w;
    float sq  = v.x*v.x + v.y*v.y + v.z*v.z + v.w*v.w;
    #pragma unroll
    for (int off = 32; off > 0; off >>= 1) {
        sum += __shfl_down(sum, off);
        sq  += __shfl_down(sq,  off);
    }
    __shared__ float s1[4], s2[4];
    const int wid = threadIdx.x >> 6;
    if ((threadIdx.x & 63) == 0) { s1[wid] = sum; s2[wid] = sq; }
    __syncthreads();
    const float tsum = s1[0] + s1[1] + s1[2] + s1[3];
    const float tsq  = s2[0] + s2[1] + s2[2] + s2[3];
    const float mean = tsum / 1024.f;
    const float var  = tsq / 1024.f - mean * mean;
    const float rstd = rsqrtf(var + 1e-5f);
    ushort4 o;
    o.x = f2b((v.x - mean) * rstd * w[c+0] + bias[c+0]);
    o.y = f2b((v.y - mean) * rstd * w[c+1] + bias[c+1]);
    o.z = f2b((v.z - mean) * rstd * w[c+2] + bias[c+2]);
    o.w = f2b((v.w - mean) * rstd * w[c+3] + bias[c+3]);
    *reinterpret_cast<ushort4*>(&out[row * 1024 + c]) = o;
}

// ---------------- shared 64x64 GEMM core (device, 4 waves) ------------------
__device__ __forceinline__ void gemm64_core(
    const u16* __restrict__ A, const u16* __restrict__ W, void* __restrict__ C,
    int ob, int N, int K, int m0, int n0, u16* As, u16* Ws)
{
    constexpr int PF = 3, LPT = 2, RD = 4;
    const int tid  = threadIdx.x;
    const int lane = tid & 63;
    const int wave = tid >> 6;
    const int wr = wave >> 1, wc = wave & 1;

    const int srow = tid >> 2;
    const int scol = (((tid & 3) ^ ((srow >> 1) & 3))) * 8;
    const u16* Ag = A + (size_t)(m0 + srow) * K + scol;
    const u16* Wg = W + (size_t)(n0 + srow) * K + scol;

    const int fr = lane & 15;
    const int fq = lane >> 4;

    f32x4 acc[2][2] = {};

    auto stage = [&](int buf, int k0) {
        gload16(Ag + k0, &As[buf * 2048 + tid * 8]);
        gload16(Wg + k0, &Ws[buf * 2048 + tid * 8]);
    };
    auto compute = [&](int buf) {
        short8 a[2], b[2];
        #pragma unroll
        for (int m = 0; m < 2; ++m) {
            const int r = wr * 32 + m * 16 + fr;
            a[m] = *reinterpret_cast<const short8*>(&As[buf * 2048 + aswz(r, fq)]);
        }
        #pragma unroll
        for (int n = 0; n < 2; ++n) {
            const int r = wc * 32 + n * 16 + fr;
            b[n] = *reinterpret_cast<const short8*>(&Ws[buf * 2048 + aswz(r, fq)]);
        }
        #pragma unroll
        for (int m = 0; m < 2; ++m)
            #pragma unroll
            for (int n = 0; n < 2; ++n)
                acc[m][n] = __builtin_amdgcn_mfma_f32_16x16x32_bf16(
                    a[m], b[n], acc[m][n], 0, 0, 0);
    };

    const int nt = K / 32;
    #pragma unroll
    for (int i = 0; i < PF; ++i) stage(i, i * 32);

    int cbuf = 0, sbuf = PF;
    for (int t = 0; t <= nt - PF; ++t) {
        asm volatile("s_waitcnt vmcnt(%0)\n\ts_barrier"
                     :: "n"((PF - 1) * LPT) : "memory");
        if (t + PF < nt) {
            stage(sbuf, (t + PF) * 32);
            if (++sbuf == RD) sbuf = 0;
        }
        compute(cbuf);
        if (++cbuf == RD) cbuf = 0;
    }
    #pragma unroll
    for (int i = 1; i < PF; ++i) {
        asm volatile("s_waitcnt vmcnt(%0)\n\ts_barrier"
                     :: "n"((PF - 1 - i) * LPT) : "memory");
        compute(cbuf);
        if (++cbuf == RD) cbuf = 0;
    }

    #pragma unroll
    for (int m = 0; m < 2; ++m)
        #pragma unroll
        for (int j = 0; j < 4; ++j) {
            const size_t row = (size_t)(m0 + wr * 32 + m * 16 + fq * 4 + j);
            #pragma unroll
            for (int n = 0; n < 2; ++n) {
                const size_t idx = row * (size_t)N + (size_t)(n0 + wc * 32 + n * 16 + fr);
                if (ob) ((u16*)C)[idx]  = f2b(acc[m][n][j]);
                else    ((float*)C)[idx] = acc[m][n][j];
            }
        }
}

// -------------- 8-wave 128x128 GEMM core (512 threads, PF=2) ----------------
__device__ __forceinline__ void gemm8_core(
    const u16* __restrict__ A, const u16* __restrict__ W, void* __restrict__ C,
    int ob, int epi, int N, int Kstride, int kcnt, int m0, int n0,
    u16* As, u16* Ws)
{
    constexpr int PF = 2, LPT = 2, RD = 3;
    const int tid  = threadIdx.x;        // 0..511
    const int lane = tid & 63;
    const int wave = tid >> 6;           // 0..7
    const int wr = wave >> 2, wc = wave & 3;

    const int srow = tid >> 2;           // 0..127
    const int scol = (((tid & 3) ^ ((srow >> 1) & 3))) * 8;
    const u16* Ag = A + (size_t)(m0 + srow) * Kstride + scol;
    const u16* Wg = W + (size_t)(n0 + srow) * Kstride + scol;

    const int fr = lane & 15;
    const int fq = lane >> 4;

    f32x4 acc[4][2] = {};

    auto stage = [&](int buf, int k0) {
        gload16(Ag + k0, &As[buf * 4096 + tid * 8]);
        gload16(Wg + k0, &Ws[buf * 4096 + tid * 8]);
    };
    auto compute = [&](int buf) {
        short8 a[4], b[2];
        #pragma unroll
        for (int m = 0; m < 4; ++m) {
            const int r = wr * 64 + m * 16 + fr;
            a[m] = *reinterpret_cast<const short8*>(&As[buf * 4096 + aswz(r, fq)]);
        }
        #pragma unroll
        for (int n = 0; n < 2; ++n) {
            const int r = wc * 32 + n * 16 + fr;
            b[n] = *reinterpret_cast<const short8*>(&Ws[buf * 4096 + aswz(r, fq)]);
        }
        #pragma unroll
        for (int m = 0; m < 4; ++m)
            #pragma unroll
            for (int n = 0; n < 2; ++n)
                acc[m][n] = __builtin_amdgcn_mfma_f32_16x16x32_bf16(
                    a[m], b[n], acc[m][n], 0, 0, 0);
    };

    const int nt = kcnt / 32;
    #pragma unroll
    for (int i = 0; i < PF; ++i) stage(i, i * 32);

    int cbuf = 0, sbuf = PF;
    for (int t = 0; t <= nt - PF; ++t) {
        asm volatile("s_waitcnt vmcnt(%0)\n\ts_barrier"
                     :: "n"((PF - 1) * LPT) : "memory");
        if (t + PF < nt) {
            stage(sbuf, (t + PF) * 32);
            if (++sbuf == RD) sbuf = 0;
        }
        compute(cbuf);
        if (++cbuf == RD) cbuf = 0;
    }
    asm volatile("s_waitcnt vmcnt(0)\n\ts_barrier" ::: "memory");
    compute(cbuf);

    #pragma unroll
    for (int m = 0; m < 4; ++m)
        #pragma unroll
        for (int j = 0; j < 4; ++j) {
            const size_t row = (size_t)(m0 + wr * 64 + m * 16 + fq * 4 + j);
            #pragma unroll
            for (int n = 0; n < 2; ++n) {
                float v = acc[m][n][j];
                if (epi == 1) v = 0.5f * v * (1.f + erff(v * 0.70710678118654752f));
                const size_t idx = row * (size_t)N + (size_t)(n0 + wc * 32 + n * 16 + fr);
                if (ob) ((u16*)C)[idx]  = f2b(v);
                else    ((float*)C)[idx] = v;
            }
        }
}

// ------------- 8-wave 128x64 GEMM core (512 threads, PF=2) ------------------
// Wave grid 4x2: wave tile 32x32, acc 2x2. LDS = 3*(8KB A + 4KB W) = 36 KB ->
// 4 blocks/CU = 32 waves/CU (the CU max). A staged by all 512 threads (1 load
// each); W staged by threads 0..255 (1 load). Per-wave vmcnt: waves 0-3 have
// 2 loads/tile (vmcnt 2), waves 4-7 have 1 (vmcnt 1) -- wave-uniform branch.
__device__ __forceinline__ void gemm8x64_core(
    const u16* __restrict__ A, const u16* __restrict__ W, void* __restrict__ C,
    int ob, int epi, int N, int Kstride, int kcnt, int m0, int n0,
    u16* As, u16* Ws)
{
    const int tid  = threadIdx.x;        // 0..511
    const int lane = tid & 63;
    const int wave = tid >> 6;           // 0..7
    const int wr = wave >> 1, wc = wave & 1;   // 4x2 wave grid

    const int srow = tid >> 2;           // A row 0..127 (W row 0..63 for tid<256)
    const int scol = (((tid & 3) ^ ((srow >> 1) & 3))) * 8;
    const u16* Ag = A + (size_t)(m0 + srow) * Kstride + scol;
    const bool wst = (tid < 256);
    const u16* Wg = W + (size_t)(n0 + srow) * Kstride + scol;  // valid for tid<256

    const int fr = lane & 15;
    const int fq = lane >> 4;

    f32x4 acc[2][2] = {};

    auto stage = [&](int buf, int k0) {
        gload16(Ag + k0, &As[buf * 4096 + tid * 8]);
        if (wst) gload16(Wg + k0, &Ws[buf * 2048 + tid * 8]);
    };
    auto compute = [&](int buf) {
        short8 a[2], b[2];
        #pragma unroll
        for (int m = 0; m < 2; ++m) {
            const int r = wr * 32 + m * 16 + fr;
            a[m] = *reinterpret_cast<const short8*>(&As[buf * 4096 + aswz(r, fq)]);
        }
        #pragma unroll
        for (int n = 0; n < 2; ++n) {
            const int r = wc * 32 + n * 16 + fr;
            b[n] = *reinterpret_cast<const short8*>(&Ws[buf * 2048 + aswz(r, fq)]);
        }
        #pragma unroll
        for (int m = 0; m < 2; ++m)
            #pragma unroll
            for (int n = 0; n < 2; ++n)
                acc[m][n] = __builtin_amdgcn_mfma_f32_16x16x32_bf16(
                    a[m], b[n], acc[m][n], 0, 0, 0);
    };

    const int nt = kcnt / 32;
    stage(0, 0);
    stage(1, 32);

    int cbuf = 0, sbuf = 2;
    for (int t = 0; t <= nt - 2; ++t) {
        // drain tile t's own loads (per-wave count), then barrier
        if (wave < 4) asm volatile("s_waitcnt vmcnt(2)\n\ts_barrier" ::: "memory");
        else          asm volatile("s_waitcnt vmcnt(1)\n\ts_barrier" ::: "memory");
        if (t + 2 < nt) {
            stage(sbuf, (t + 2) * 32);
            if (++sbuf == 3) sbuf = 0;
        }
        compute(cbuf);
        if (++cbuf == 3) cbuf = 0;
    }
    asm volatile("s_waitcnt vmcnt(0)\n\ts_barrier" ::: "memory");
    compute(cbuf);

    #pragma unroll
    for (int m = 0; m < 2; ++m)
        #pragma unroll
        for (int j = 0; j < 4; ++j) {
            const size_t row = (size_t)(m0 + wr * 32 + m * 16 + fq * 4 + j);
            #pragma unroll
            for (int n = 0; n < 2; ++n) {
                float v = acc[m][n][j];
                if (epi == 1) v = 0.5f * v * (1.f + erff(v * 0.70710678118654752f));
                const size_t idx = row * (size_t)N + (size_t)(n0 + wc * 32 + n * 16 + fr);
                if (ob) ((u16*)C)[idx]  = f2b(v);
                else    ((float*)C)[idx] = v;
            }
        }
}

__global__ __launch_bounds__(512)
void gemm8(const u16* __restrict__ A, const u16* __restrict__ W,
           void* __restrict__ Cv, int N, int K, int ob, int epi, int kchunk)
{
    __shared__ __align__(16) u16 As[3][4096];
    __shared__ __align__(16) u16 Ws[3][4096];
    const int nwg = gridDim.x * gridDim.y;
    const int bid = blockIdx.y * gridDim.x + blockIdx.x;
    const int nid = (bid & 7) * (nwg >> 3) + (bid >> 3);
    const int by  = nid % gridDim.y;
    const int bx  = nid / gridDim.y;
    const int kz  = blockIdx.z * kchunk;
    void* C = ob ? Cv : (void*)((float*)Cv + (size_t)blockIdx.z * M_ROWS * N);
    gemm8_core(A + kz, W + kz, C, ob, epi, N, K, kchunk,
               by * 128, bx * 128, &As[0][0], &Ws[0][0]);
}

// 8-wave 128x64 standalone kernel (fc1, fc2 split-K): grid (N/64, M/128, z)
__global__ __launch_bounds__(512)
void gemm8n64(const u16* __restrict__ A, const u16* __restrict__ W,
              void* __restrict__ Cv, int N, int K, int ob, int epi, int kchunk)
{
    __shared__ __align__(16) u16 As[3][4096];
    __shared__ __align__(16) u16 Ws[3][2048];
    const int nwg = gridDim.x * gridDim.y;
    const int bid = blockIdx.y * gridDim.x + blockIdx.x;
    const int nid = (bid & 7) * (nwg >> 3) + (bid >> 3);
    const int by  = nid % gridDim.y;
    const int bx  = nid / gridDim.y;
    const int kz  = blockIdx.z * kchunk;
    void* C = ob ? Cv : (void*)((float*)Cv + (size_t)blockIdx.z * M_ROWS * N);
    gemm8x64_core(A + kz, W + kz, C, ob, epi, N, K, kchunk,
                  by * 128, bx * 64, &As[0][0], &Ws[0][0]);
}

struct GemmPack4 { const u16* A[4]; const u16* W[4]; u16* C[4]; int N[4]; };

__global__ __launch_bounds__(512)
void gemm8_bat4(GemmPack4 p)
{
    __shared__ __align__(16) u16 As[3][4096];
    __shared__ __align__(16) u16 Ws[3][4096];
    constexpr int pre[5] = {0, 192, 256, 384, 576};
    const int nwg = gridDim.x * gridDim.y;           // 576
    const int bid = blockIdx.y * gridDim.x + blockIdx.x;
    const int nid = (bid & 7) * (nwg >> 3) + (bid >> 3);
    int seg = 0;
    #pragma unroll
    for (int i = 1; i < 4; ++i) seg += (nid >= pre[i]);
    const int idx = nid - pre[seg];
    const int nx  = p.N[seg] >> 7;
    const int bx  = idx % nx;
    const int by  = idx / nx;
    gemm8_core(p.A[seg], p.W[seg], p.C[seg], 1, 0, p.N[seg], 1024, 1024,
               by * 128, bx * 128, &As[0][0], &Ws[0][0]);
}

// ------------------------------ MFMA GEMM ----------------------------------
template<int BM, int BN, int EPI, int OB>
__global__ __launch_bounds__(256)
void gemm_mfma(const u16* __restrict__ A, const u16* __restrict__ W,
               void* __restrict__ Cv, int N, int K,
               const float* __restrict__ gatep, int kchunk)
{
    constexpr int MF  = BM / 32;
    constexpr int NF  = BN / 32;
    constexpr int LPT = BM / 64 + BN / 64;
    constexpr int PF  = 3;
    constexpr int RD  = 4;
    __shared__ __align__(16) u16 As[RD][BM * 32];
    __shared__ __align__(16) u16 Ws[RD][BN * 32];
    const int tid  = threadIdx.x;
    const int lane = tid & 63;
    const int wave = tid >> 6;
    const int wr = wave >> 1, wc = wave & 1;

    const int nwg = gridDim.x * gridDim.y;
    const int bid = blockIdx.y * gridDim.x + blockIdx.x;
    const int nid = (bid & 7) * (nwg >> 3) + (bid >> 3);
    const int by  = nid % gridDim.y;
    const int bx  = nid / gridDim.y;
    const int m0 = by * BM, n0 = bx * BN;
    const int kz = blockIdx.z * kchunk;

    const int srow = tid >> 2;
    const int scol = (((tid & 3) ^ ((srow >> 1) & 3))) * 8;
    const u16* Ag = A + (size_t)(m0 + srow) * K + scol + kz;
    const u16* Wg = W + (size_t)(n0 + srow) * K + scol + kz;

    const int fr = lane & 15;
    const int fq = lane >> 4;

    f32x4 acc[MF][NF] = {};

    auto stage = [&](int buf, int k0) {
        #pragma unroll
        for (int i = 0; i < BM / 64; ++i)
            gload16(Ag + k0 + (size_t)(i * 64) * K, &As[buf][tid * 8 + i * 2048]);
        #pragma unroll
        for (int i = 0; i < BN / 64; ++i)
            gload16(Wg + k0 + (size_t)(i * 64) * K, &Ws[buf][tid * 8 + i * 2048]);
    };
    auto compute = [&](int buf) {
        short8 a[MF], b[NF];
        #pragma unroll
        for (int m = 0; m < MF; ++m) {
            const int r = wr * (BM / 2) + m * 16 + fr;
            a[m] = *reinterpret_cast<const short8*>(&As[buf][aswz(r, fq)]);
        }
        #pragma unroll
        for (int n = 0; n < NF; ++n) {
            const int r = wc * (BN / 2) + n * 16 + fr;
            b[n] = *reinterpret_cast<const short8*>(&Ws[buf][aswz(r, fq)]);
        }
        #pragma unroll
        for (int m = 0; m < MF; ++m)
            #pragma unroll
            for (int n = 0; n < NF; ++n)
                acc[m][n] = __builtin_amdgcn_mfma_f32_16x16x32_bf16(
                    a[m], b[n], acc[m][n], 0, 0, 0);
    };

    const int nt = kchunk / 32;
    #pragma unroll
    for (int i = 0; i < PF; ++i) stage(i, i * 32);

    int cbuf = 0, sbuf = PF;
    for (int t = 0; t <= nt - PF; ++t) {
        asm volatile("s_waitcnt vmcnt(%0)\n\ts_barrier"
                     :: "n"((PF - 1) * LPT) : "memory");
        if (t + PF < nt) {
            stage(sbuf, (t + PF) * 32);
            if (++sbuf == RD) sbuf = 0;
        }
        compute(cbuf);
        if (++cbuf == RD) cbuf = 0;
    }
    #pragma unroll
    for (int i = 1; i < PF; ++i) {
        asm volatile("s_waitcnt vmcnt(%0)\n\ts_barrier"
                     :: "n"((PF - 1 - i) * LPT) : "memory");
        compute(cbuf);
        if (++cbuf == RD) cbuf = 0;
    }

    float* Cz = (float*)Cv + (size_t)blockIdx.z * M_ROWS * N;
    const float gate = (EPI == 2) ? gatep[0] : 0.f;
    #pragma unroll
    for (int m = 0; m < MF; ++m) {
        #pragma unroll
        for (int j = 0; j < 4; ++j) {
            const size_t row = (size_t)(m0 + wr * (BM / 2) + m * 16 + fq * 4 + j);
            #pragma unroll
            for (int n = 0; n < NF; ++n) {
                float v = acc[m][n][j];
                const size_t idx = row * (size_t)N + (size_t)(n0 + wc * (BN / 2) + n * 16 + fr);
                if (EPI == 1) v = 0.5f * v * (1.f + erff(v * 0.70710678118654752f));
                if (OB) {
                    ((u16*)Cv)[idx] = f2b(v);
                } else {
                    if (EPI == 2) Cz[idx] = Cz[idx] + gate * v;
                    else          Cz[idx] = v;
                }
            }
        }
    }
}

// -------- batched gate-path GEMMs: wt_out + gq + gk + gv (K=512) ------------
struct GemmPack4b { const u16* A[4]; const u16* W[4]; void* C[4]; int N[4]; int ob[4]; };

__global__ __launch_bounds__(256)
void gemm_bat4b(GemmPack4b p)
{
    __shared__ __align__(16) u16 As[4][2048];
    __shared__ __align__(16) u16 Ws[4][2048];
    constexpr int pre[5] = {0, 512, 768, 1024, 1280};
    const int nwg = gridDim.x * gridDim.y;           // 1280
    const int bid = blockIdx.y * gridDim.x + blockIdx.x;
    const int nid = (bid & 7) * (nwg >> 3) + (bid >> 3);
    int seg = 0;
    #pragma unroll
    for (int i = 1; i < 4; ++i) seg += (nid >= pre[i]);
    const int idx = nid - pre[seg];
    const int nx  = p.N[seg] >> 6;
    const int bx  = idx % nx;
    const int by  = idx / nx;
    gemm64_core(p.A[seg], p.W[seg], p.C[seg], p.ob[seg], p.N[seg], 512,
                by * 64, bx * 64, &As[0][0], &Ws[0][0]);
}

// ---------------- split-K reduce: C += gate * (p0+p1+p2+p3) ----------------
__global__ __launch_bounds__(256)
void redk(const float* __restrict__ p, const float* __restrict__ gatep,
          float* __restrict__ C)
{
    const int i = (blockIdx.x * 256 + threadIdx.x) * 4;
    const float g = gatep[0];
    const float4 a = *reinterpret_cast<const float4*>(p + i);
    const float4 b = *reinterpret_cast<const float4*>(p + 2097152 + i);
    const float4 c = *reinterpret_cast<const float4*>(p + 4194304 + i);
    const float4 d = *reinterpret_cast<const float4*>(p + 6291456 + i);
    float4 o = *reinterpret_cast<float4*>(C + i);
    o.x += g * ((a.x + b.x) + (c.x + d.x));
    o.y += g * ((a.y + b.y) + (c.y + d.y));
    o.z += g * ((a.z + b.z) + (c.z + d.z));
    o.w += g * ((a.w + b.w) + (c.w + d.w));
    *reinterpret_cast<float4*>(C + i) = o;
}

// ------------------------- MFMA fused attention ----------------------------
struct AttnPack {
    const u16* Q[3]; const u16* K[3]; const u16* V[3]; void* O[3];
    int qs[3], ks[3], vs[3], os[3], ob[3];
};

__global__ __launch_bounds__(256)
void attn_mfma(AttnPack p, int NP)
{
    const int nwg = gridDim.x * gridDim.y;
    const int bid = blockIdx.y * gridDim.x + blockIdx.x;
    const int nid = (bid & 7) * (nwg >> 3) + (bid >> 3);
    const int z  = nid % NP;
    const int r_ = nid / NP;                 // [0,256)
    const int qt = r_ & 15;
    const int bh = r_ >> 4;

    const u16* __restrict__ Q = p.Q[z];
    const u16* __restrict__ K = p.K[z];
    const u16* __restrict__ V = p.V[z];
    void* __restrict__ Ov = p.O[z];
    const int qs = p.qs[z], ks = p.ks[z], vs = p.vs[z], os = p.os[z];
    const int ob = p.ob[z];

    __shared__ __align__(16) u16 Ks[2][128 * 32];  // [half*64+kv][32]
    __shared__ __align__(16) u16 Vt[2][128 * 32];  // [half*64+d][32]
    __shared__ __align__(16) u16 Ps[4][32 * 32];   // per-wave [half*16+q][32]
    const int tid  = threadIdx.x;
    const int lane = tid & 63;
    const int wave = tid >> 6;
    const int fr = lane & 15;
    const int fq = lane >> 4;

    const int b   = bh >> 3;
    const int hc  = (bh & 7) * 64;
    const size_t qrow0 = (size_t)b * SEQ + (size_t)qt * 64;
    const size_t krow0 = (size_t)b * SEQ;

    const float SC = 0.125f * 1.44269504088896f;   // scale * log2(e)

    short8 qf[2];
    {
        const u16* qp = Q + (qrow0 + wave * 16 + fr) * qs + hc + fq * 8;
        qf[0] = *reinterpret_cast<const short8*>(qp);
        qf[1] = *reinterpret_cast<const short8*>(qp + 32);
    }

    const int skr = tid >> 2;
    const int skc = (tid & 3) * 16;
    const int svk = (tid >> 4) * 4;
    const int svd = (tid & 15) * 4;

    const int kprow = (skc >= 32 ? 64 : 0) + skr;
    const int kc0   = (skc & 31) >> 3;
    const int vbase  = (svk >= 32) ? 64 : 0;
    const int vchunk = (svk & 31) >> 3;
    const int vpos   = svk & 7;

    short8 kreg0, kreg1;
    ushort4 vr0, vr1, vr2, vr3;
    auto load_tile = [&](int kt) {
        const u16* kp = K + (krow0 + kt * 64 + skr) * ks + hc + skc;
        kreg0 = *reinterpret_cast<const short8*>(kp);
        kreg1 = *reinterpret_cast<const short8*>(kp + 8);
        const u16* vp = V + (krow0 + kt * 64 + svk) * vs + hc + svd;
        vr0 = *reinterpret_cast<const ushort4*>(vp);
        vr1 = *reinterpret_cast<const ushort4*>(vp + vs);
        vr2 = *reinterpret_cast<const ushort4*>(vp + 2 * (size_t)vs);
        vr3 = *reinterpret_cast<const ushort4*>(vp + 3 * (size_t)vs);
    };
    auto write_tile = [&](int bf) {
        *reinterpret_cast<short8*>(&Ks[bf][aswz(kprow, kc0)])     = kreg0;
        *reinterpret_cast<short8*>(&Ks[bf][aswz(kprow, kc0 + 1)]) = kreg1;
        uint2 w;
        #pragma unroll
        for (int i = 0; i < 4; ++i) {
            u16* dst = &Vt[bf][aswz(vbase + svd + i, vchunk) + vpos];
            unsigned lo, hi;
            if (i == 0) { lo = (unsigned)vr0.x | ((unsigned)vr1.x << 16);
                          hi = (unsigned)vr2.x | ((unsigned)vr3.x << 16); }
            else if (i == 1) { lo = (unsigned)vr0.y | ((unsigned)vr1.y << 16);
                               hi = (unsigned)vr2.y | ((unsigned)vr3.y << 16); }
            else if (i == 2) { lo = (unsigned)vr0.z | ((unsigned)vr1.z << 16);
                               hi = (unsigned)vr2.z | ((unsigned)vr3.z << 16); }
            else { lo = (unsigned)vr0.w | ((unsigned)vr1.w << 16);
                   hi = (unsigned)vr2.w | ((unsigned)vr3.w << 16); }
            w.x = lo; w.y = hi;
            *reinterpret_cast<uint2*>(dst) = w;
        }
    };

    float m_run = -1e30f, l_run = 0.f;     // exp2-scaled domain
    f32x4 acc[4] = {};

    load_tile(0);
    write_tile(0);
    __syncthreads();

    constexpr int NT = SEQ / 64;
    for (int kt = 0; kt < NT; ++kt) {
        const int bf = kt & 1;
        if (kt + 1 < NT) load_tile(kt + 1);

        f32x4 st[4] = {};
        __builtin_amdgcn_s_setprio(1);
        #pragma unroll
        for (int kn = 0; kn < 4; ++kn) {
            const int r = kn * 16 + fr;
            const short8 ka0 = *reinterpret_cast<const short8*>(
                &Ks[bf][aswz(r, fq)]);
            const short8 ka1 = *reinterpret_cast<const short8*>(
                &Ks[bf][aswz(64 + r, fq)]);
            st[kn] = __builtin_amdgcn_mfma_f32_16x16x32_bf16(ka0, qf[0], st[kn], 0, 0, 0);
            st[kn] = __builtin_amdgcn_mfma_f32_16x16x32_bf16(ka1, qf[1], st[kn], 0, 0, 0);
        }
        __builtin_amdgcn_s_setprio(0);

        float mx = -1e30f;
        #pragma unroll
        for (int kn = 0; kn < 4; ++kn)
            #pragma unroll
            for (int r = 0; r < 4; ++r) {
                st[kn][r] *= SC;                       // exp2 domain
                mx = fmaxf(mx, st[kn][r]);
            }
        mx = fmaxf(mx, __shfl_xor(mx, 16, 64));
        mx = fmaxf(mx, __shfl_xor(mx, 32, 64));

        // defer-max (T13): keep old max if growth <= 8 (P bounded by 2^8).
        const bool noresc = __all(mx <= m_run + 8.f);
        const float mold = m_run;
        const float mnew = noresc ? m_run : fmaxf(m_run, mx);
        m_run = mnew;

        float psum = 0.f;
        #pragma unroll
        for (int kn = 0; kn < 4; ++kn) {
            const float p0 = exp2f(st[kn][0] - mnew);
            const float p1 = exp2f(st[kn][1] - mnew);
            const float p2 = exp2f(st[kn][2] - mnew);
            const float p3 = exp2f(st[kn][3] - mnew);
            psum += (p0 + p1) + (p2 + p3);
            uint2 w;
            w.x = cvtpk_bf16(p0, p1);
            w.y = cvtpk_bf16(p2, p3);
            const int prow = (kn >> 1) * 16 + fr;
            const int pcol = (kn & 1) * 16 + fq * 4;
            *reinterpret_cast<uint2*>(
                &Ps[wave][aswz(prow, pcol >> 3) + (pcol & 7)]) = w;
        }
        psum += __shfl_xor(psum, 16, 64);
        psum += __shfl_xor(psum, 32, 64);

        if (noresc) {
            l_run += psum;
        } else {
            const float corr = exp2f(mold - mnew);
            l_run = l_run * corr + psum;
            float cq[4];
            #pragma unroll
            for (int j = 0; j < 4; ++j) cq[j] = __shfl(corr, fq * 4 + j, 64);
            #pragma unroll
            for (int nd = 0; nd < 4; ++nd)
                #pragma unroll
                for (int j = 0; j < 4; ++j)
                    acc[nd][j] *= cq[j];
        }

        short8 pa0 = *reinterpret_cast<const short8*>(&Ps[wave][aswz(fr, fq)]);
        short8 pa1 = *reinterpret_cast<const short8*>(&Ps[wave][aswz(16 + fr, fq)]);
        __builtin_amdgcn_s_setprio(1);
        #pragma unroll
        for (int nd = 0; nd < 4; ++nd) {
            const int d = nd * 16 + fr;
            const short8 vb0 = *reinterpret_cast<const short8*>(
                &Vt[bf][aswz(d, fq)]);
            const short8 vb1 = *reinterpret_cast<const short8*>(
                &Vt[bf][aswz(64 + d, fq)]);
            acc[nd] = __builtin_amdgcn_mfma_f32_16x16x32_bf16(pa0, vb0, acc[nd], 0, 0, 0);
            acc[nd] = __builtin_amdgcn_mfma_f32_16x16x32_bf16(pa1, vb1, acc[nd], 0, 0, 0);
        }
        __builtin_amdgcn_s_setprio(0);

        if (kt + 1 < NT) write_tile(bf ^ 1);
        __syncthreads();
    }

    float iq[4];
    #pragma unroll
    for (int j = 0; j < 4; ++j) iq[j] = 1.f / __shfl(l_run, fq * 4 + j, 64);
    #pragma unroll
    for (int j = 0; j < 4; ++j) {
        const size_t orow = (qrow0 + wave * 16 + fq * 4 + j) * os + hc;
        #pragma unroll
        for (int nd = 0; nd < 4; ++nd) {
            const float v = acc[nd][j] * iq[j];
            if (ob) ((u16*)Ov)[orow + nd * 16 + fr] = f2b(v);
            else    ((float*)Ov)[orow + nd * 16 + fr] = v;
        }
    }
}

// ------- gate mix (dot over summed split-K planes, softmax-2, blend) -------
__global__ __launch_bounds__(256)
void mix_kernel(const float* __restrict__ gpart, const float* __restrict__ mixw,
                const float* __restrict__ mixb, const float* __restrict__ so,
                const float* __restrict__ co, u16* __restrict__ mixed)
{
    const size_t row = blockIdx.x;
    const float* g0 = gpart + row * 512;
    const float* g1 = g0 + 1048576;
    float d0 = 0.f, d1 = 0.f;
    for (int c = threadIdx.x; c < 512; c += 256) {
        const float gv = g0[c] + g1[c];
        d0 = fmaf(gv, mixw[c], d0);
        d1 = fmaf(gv, mixw[512 + c], d1);
    }
    #pragma unroll
    for (int off = 32; off > 0; off >>= 1) {
        d0 += __shfl_down(d0, off);
        d1 += __shfl_down(d1, off);
    }
    __shared__ float sA[4], sB[4];
    const int wid = threadIdx.x >> 6;
    if ((threadIdx.x & 63) == 0) { sA[wid] = d0; sB[wid] = d1; }
    __syncthreads();
    const float t0 = sA[0] + sA[1] + sA[2] + sA[3] + mixb[0];
    const float t1 = sB[0] + sB[1] + sB[2] + sB[3] + mixb[1];
    const float mx = fmaxf(t0, t1);
    const float e0 = __expf(t0 - mx), e1 = __expf(t1 - mx);
    const float inv = 1.f / (e0 + e1);
    const float w0 = e0 * inv, w1 = e1 * inv;
    for (int c = threadIdx.x; c < 512; c += 256)
        mixed[row * 512 + c] = f2b(w0 * so[row * 512 + c] + w1 * co[row * 512 + c]);
}

// ---------------------------------------------------------------------------
extern "C" void kernel_launch(void* const* d_in, const int* in_sizes, int n_in,
                              void* d_out, int out_size, void* d_ws, size_t ws_size,
                              hipStream_t stream)
{
    const float* query     = (const float*)d_in[0];
    const float* kvwt      = (const float*)d_in[1];
    const float* nq_w      = (const float*)d_in[2];
    const float* nq_b      = (const float*)d_in[3];
    const float* nkv_w     = (const float*)d_in[4];
    const float* nkv_b     = (const float*)d_in[5];
    const float* wq_cross  = (const float*)d_in[6];
    const float* wkv_cross = (const float*)d_in[7];
    const float* wqkv_self = (const float*)d_in[8];
    const float* gn_w      = (const float*)d_in[9];
    const float* gn_b      = (const float*)d_in[10];
    const float* mha_in_w  = (const float*)d_in[11];
    const float* mha_out_w = (const float*)d_in[12];
    const float* mix_w     = (const float*)d_in[13];
    const float* mix_b     = (const float*)d_in[14];
    const float* w_out     = (const float*)d_in[15];
    const float* ff_ln_w   = (const float*)d_in[16];
    const float* ff_ln_b   = (const float*)d_in[17];
    const float* ff_fc1    = (const float*)d_in[18];
    const float* ff_fc2    = (const float*)d_in[19];
    const float* ff_gate   = (const float*)d_in[20];

    float* delta_out = (float*)d_out;                          // stack[0]
    float* wt_out    = (float*)d_out + (size_t)M_ROWS * 1024;  // stack[1]

    // ---- workspace layout (byte offsets; high-water 68,157,440 B) ----
    char* wsb = (char*)d_ws;
    u16*   qkv_b   = (u16*)  (wsb + 0);
    u16*   kv_c_b  = (u16*)  (wsb + 6291456);
    u16*   q_c_b   = (u16*)  (wsb + 10485760);
    float* cross_f = (float*)(wsb + 12582912);
    float* self_f  = (float*)(wsb + 16777216);
    u16*   kvn_b   = (u16*)  (wsb + 20971520);
    u16*   qn_b    = (u16*)  (wsb + 25165824);
    u16*   wta_b   = (u16*)  (wsb + 29360128);
    u16*   con_b   = (u16*)  (wsb + 31457280);
    u16*   gq_b    = qkv_b;
    u16*   gk_b    = qkv_b + 1048576;
    u16*   gv_b    = qkv_b + 2097152;
    u16*   gattn_b = kvn_b;
    u16*   mixed_b = kvn_b + 1048576;
    u16*   lnd_b   = qn_b;
    u16*   ffh_b   = qkv_b;
    float* part_f  = (float*)(wsb + 16777216);   // fc2 partials (step 19)
    float* gpart_f = (float*)(wsb + 0);          // gctx split-K partials: 2x4MB
    float* dpart_f = (float*)(wsb + 0);          // delta split-K partials: 2x8MB
    u16*   qkv_s_b = (u16*)  (wsb + 59768832);
    u16*   son_b   = (u16*)  (wsb + 66060288);
    u16* wqkv_self_b = (u16*)(wsb + 33554432);
    u16* wq_cross_b  = (u16*)(wsb + 36700160);
    u16* wkv_cross_b = (u16*)(wsb + 37748736);
    u16* mha_in_b    = (u16*)(wsb + 39845888);
    u16* mha_out_b   = (u16*)(wsb + 41418752);
    u16* w_out_b     = (u16*)(wsb + 41943040);
    u16* ff_fc1_b    = (u16*)(wsb + 42991616);
    u16* ff_fc2_b    = (u16*)(wsb + 51380224);

    const dim3 blk(256);
    const dim3 blk8(512);

    // 0. fused weight conversion
    CvtPack cp;
    cp.s[0] = wqkv_self; cp.d[0] = wqkv_self_b;
    cp.s[1] = wq_cross;  cp.d[1] = wq_cross_b;
    cp.s[2] = wkv_cross; cp.d[2] = wkv_cross_b;
    cp.s[3] = mha_in_w;  cp.d[3] = mha_in_b;
    cp.s[4] = mha_out_w; cp.d[4] = mha_out_b;
    cp.s[5] = w_out;     cp.d[5] = w_out_b;
    cp.s[6] = ff_fc1;    cp.d[6] = ff_fc1_b;
    cp.s[7] = ff_fc2;    cp.d[7] = ff_fc2_b;
    cvt8_kernel<<<dim3(12800), blk, 0, stream>>>(cp);

    // 1+5. kvn = LN(kv_feats_wt), qn = LN(query)
    ln_dual<<<dim3(2 * M_ROWS), blk, 0, stream>>>(
        kvwt, nkv_w, nkv_b, kvn_b, query, nq_w, nq_b, qn_b, 1024);

    // 2,6,7,9: four projection GEMMs, 8-wave 128x128 (grid 576)
    GemmPack4 g4;
    g4.A[0] = kvn_b; g4.W[0] = wqkv_self_b; g4.C[0] = qkv_b;   g4.N[0] = 1536;
    g4.A[1] = qn_b;  g4.W[1] = wq_cross_b;  g4.C[1] = q_c_b;   g4.N[1] = 512;
    g4.A[2] = kvn_b; g4.W[2] = wkv_cross_b; g4.C[2] = kv_c_b;  g4.N[2] = 1024;
    g4.A[3] = qn_b;  g4.W[3] = wqkv_self_b; g4.C[3] = qkv_s_b; g4.N[3] = 1536;
    gemm8_bat4<<<dim3(18, 32), blk8, 0, stream>>>(g4);

    // 3,8,10: three attentions, problem index in fast bits (grid 48x16)
    AttnPack ap;
    ap.Q[0] = qkv_b;    ap.K[0] = qkv_b + 512;    ap.V[0] = qkv_b + 1024;    ap.O[0] = wta_b;
    ap.qs[0] = 1536; ap.ks[0] = 1536; ap.vs[0] = 1536; ap.os[0] = 512; ap.ob[0] = 1;
    ap.Q[1] = q_c_b;    ap.K[1] = kv_c_b;         ap.V[1] = kv_c_b + 512;    ap.O[1] = cross_f;
    ap.qs[1] = 512;  ap.ks[1] = 1024; ap.vs[1] = 1024; ap.os[1] = 512; ap.ob[1] = 0;
    ap.Q[2] = qkv_s_b;  ap.K[2] = qkv_s_b + 512;  ap.V[2] = qkv_s_b + 1024;  ap.O[2] = self_f;
    ap.qs[2] = 1536; ap.ks[2] = 1536; ap.vs[2] = 1536; ap.os[2] = 512; ap.ob[2] = 0;
    attn_mfma<<<dim3(48, 16), blk, 0, stream>>>(ap, 3);

    // 11. son = LN(self; gn), con = LN(cross; gn)
    ln_dual<<<dim3(2 * M_ROWS), blk, 0, stream>>>(
        self_f, gn_w, gn_b, son_b, cross_f, gn_w, gn_b, con_b, 512);

    // 4+12. wt_out + gq/gk/gv in ONE batched launch (grid 1280, K=512)
    GemmPack4b g4b;
    g4b.A[0] = wta_b; g4b.W[0] = w_out_b;             g4b.C[0] = wt_out; g4b.N[0] = 1024; g4b.ob[0] = 0;
    g4b.A[1] = son_b; g4b.W[1] = mha_in_b;            g4b.C[1] = gq_b;   g4b.N[1] = 512;  g4b.ob[1] = 1;
    g4b.A[2] = con_b; g4b.W[2] = mha_in_b + 512*512;  g4b.C[2] = gk_b;   g4b.N[2] = 512;  g4b.ob[2] = 1;
    g4b.A[3] = con_b; g4b.W[3] = mha_in_b + 1024*512; g4b.C[3] = gv_b;   g4b.N[3] = 512;  g4b.ob[3] = 1;
    gemm_bat4b<<<dim3(40, 32), blk, 0, stream>>>(g4b);

    // 13. gate attention (single problem)
    AttnPack gp;
    gp.Q[0] = gq_b; gp.K[0] = gk_b; gp.V[0] = gv_b; gp.O[0] = gattn_b;
    gp.qs[0] = 512; gp.ks[0] = 512; gp.vs[0] = 512; gp.os[0] = 512; gp.ob[0] = 1;
    gp.Q[1] = gp.Q[0]; gp.K[1] = gp.K[0]; gp.V[1] = gp.V[0]; gp.O[1] = gp.O[0];
    gp.qs[1] = 512; gp.ks[1] = 512; gp.vs[1] = 512; gp.os[1] = 512; gp.ob[1] = 1;
    gp.Q[2] = gp.Q[0]; gp.K[2] = gp.K[0]; gp.V[2] = gp.V[0]; gp.O[2] = gp.O[0];
    gp.qs[2] = 512; gp.ks[2] = 512; gp.vs[2] = 512; gp.os[2] = 512; gp.ob[2] = 1;
    attn_mfma<<<dim3(16, 16), blk, 0, stream>>>(gp, 1);

    // 14. gctx partials = gate_attn @ mha_out_w^T, split-K=2 (grid 512)
    gemm_mfma<64,64,0,0><<<dim3(8, 32, 2), blk, 0, stream>>>(gattn_b, mha_out_b, gpart_f, 512, 512, nullptr, 256);
    // 15. mixed = softmax-gate blend (sums gctx planes inline)
    mix_kernel<<<dim3(M_ROWS), blk, 0, stream>>>(gpart_f, mix_w, mix_b, self_f, cross_f, mixed_b);
    // 16. delta partials = mixed @ w_out^T, split-K=2 (grid 1024)
    gemm_mfma<64,64,0,0><<<dim3(16, 32, 2), blk, 0, stream>>>(mixed_b, w_out_b, dpart_f, 1024, 512, nullptr, 256);
    // 17. delta = p0+p1 -> delta_out (f32) + ff-LN -> lnd, one fused pass
    ln_sum<<<dim3(M_ROWS), blk, 0, stream>>>(dpart_f, delta_out, ff_ln_w, ff_ln_b, lnd_b);
    // 18. ffh = gelu(ln_delta @ ff_fc1^T)   8-wave 128x64, grid (64,16) = 1024
    gemm8n64<<<dim3(64, 16), blk8, 0, stream>>>(lnd_b, ff_fc1_b, ffh_b, 4096, 1024, 1, 1, 1024);
    // 19a. fc2 split-K=4 partials           8-wave 128x64, grid (16,16,4)
    gemm8n64<<<dim3(16, 16, 4), blk8, 0, stream>>>(ffh_b, ff_fc2_b, part_f, 1024, 4096, 0, 0, 1024);
    // 19b. delta += gate * sum(partials)
    redk<<<dim3(2048), blk, 0, stream>>>(part_f, ff_gate, delta_out);
}

// Round 21
// 225.429 us; speedup vs baseline: 1.0545x; 1.0545x over previous
//
#include <hip/hip_runtime.h>
#include <math.h>

// ---------------------------------------------------------------------------
// GatedCrossAttention: B=2, NQ=NK=1024, QD=KVD=OD=1024, H=8, DH=64, INNER=512
// Round 21: revert to round-18 config (measured best, 226.2 us): gemm8
// 128x128 PF=2 for projections/fc1/fc2, 4-wave 64^2 PF=3 small GEMMs, plain
// gctx/delta (no split-K), separate LN for delta. One micro-fix: attention
// softmax scales the MAX once instead of all 16 S values (fmax on raw S,
// exp2(fma(s, SC, -mnew))) — saves ~15 VALU ops/iter in the hottest kernel.
// ---------------------------------------------------------------------------

#define M_ROWS 2048   // B*NQ
#define SEQ    1024

typedef unsigned short u16;
typedef __attribute__((ext_vector_type(8))) short short8;
typedef __attribute__((ext_vector_type(4))) float f32x4;

__device__ inline u16 f2b(float f) {
    unsigned u = __builtin_bit_cast(unsigned, f);
    u += 0x7FFFu + ((u >> 16) & 1u);   // round-to-nearest-even
    return (u16)(u >> 16);
}
__device__ inline float b2f(u16 h) {
    return __builtin_bit_cast(float, (unsigned)h << 16);
}
__device__ inline unsigned cvtpk_bf16(float lo, float hi) {
    unsigned r;
    asm volatile("v_cvt_pk_bf16_f32 %0, %1, %2" : "=v"(r) : "v"(lo), "v"(hi));
    return r;
}

__device__ inline void gload16(const u16* g, u16* l) {
    __builtin_amdgcn_global_load_lds(
        (const __attribute__((address_space(1))) void*)g,
        (__attribute__((address_space(3))) void*)l, 16, 0, 0);
}

// swizzled LDS address (elem units): physical row prow of 32 elems, 8-elem
// chunk index, XOR on (prow>>1)&3  [GEMM-verified conflict-free pattern]
__device__ __forceinline__ int aswz(int prow, int chunk) {
    return prow * 32 + ((chunk ^ ((prow >> 1) & 3)) << 3);
}

// ------------------- fused f32 -> bf16 weight convert -----------------------
struct CvtPack { const float* s[8]; u16* d[8]; };

__global__ __launch_bounds__(256)
void cvt8_kernel(CvtPack p)
{
    constexpr int pre[9] = {0, 1536, 2048, 3072, 3840, 4096, 4608, 8704, 12800};
    const int b = blockIdx.x;
    int seg = 0;
    #pragma unroll
    for (int i = 1; i < 8; ++i) seg += (b >= pre[i]);
    const int off = (b - pre[seg]) * 1024 + threadIdx.x * 4;
    const float4 v = *reinterpret_cast<const float4*>(p.s[seg] + off);
    ushort4 o;
    o.x = f2b(v.x); o.y = f2b(v.y); o.z = f2b(v.z); o.w = f2b(v.w);
    *reinterpret_cast<ushort4*>(p.d[seg] + off) = o;
}

// --------------------------- dual LayerNorm --------------------------------
__global__ __launch_bounds__(256)
void ln_dual(const float* __restrict__ x0, const float* __restrict__ w0,
             const float* __restrict__ b0, u16* __restrict__ out0,
             const float* __restrict__ x1, const float* __restrict__ w1,
             const float* __restrict__ b1, u16* __restrict__ out1, int D)
{
    const int r = blockIdx.x;
    const int sel = r >= M_ROWS;
    const size_t row = sel ? r - M_ROWS : r;
    const float* x = sel ? x1 : x0;
    const float* w = sel ? w1 : w0;
    const float* bias = sel ? b1 : b0;
    u16* out = sel ? out1 : out0;
    const float* xr = x + row * (size_t)D;
    const int c = threadIdx.x * 4;
    float4 v = make_float4(0.f, 0.f, 0.f, 0.f);
    if (c < D) v = *reinterpret_cast<const float4*>(&xr[c]);
    float sum = v.x + v.y + v.z + v.w;
    float sq  = v.x*v.x + v.y*v.y + v.z*v.z + v.w*v.w;
    #pragma unroll
    for (int off = 32; off > 0; off >>= 1) {
        sum += __shfl_down(sum, off);
        sq  += __shfl_down(sq,  off);
    }
    __shared__ float s1[4], s2[4];
    const int wid = threadIdx.x >> 6;
    if ((threadIdx.x & 63) == 0) { s1[wid] = sum; s2[wid] = sq; }
    __syncthreads();
    const float tsum = s1[0] + s1[1] + s1[2] + s1[3];
    const float tsq  = s2[0] + s2[1] + s2[2] + s2[3];
    const float mean = tsum / (float)D;
    const float var  = tsq / (float)D - mean * mean;
    const float rstd = rsqrtf(var + 1e-5f);
    if (c < D) {
        ushort4 o;
        o.x = f2b((v.x - mean) * rstd * w[c+0] + bias[c+0]);
        o.y = f2b((v.y - mean) * rstd * w[c+1] + bias[c+1]);
        o.z = f2b((v.z - mean) * rstd * w[c+2] + bias[c+2]);
        o.w = f2b((v.w - mean) * rstd * w[c+3] + bias[c+3]);
        *reinterpret_cast<ushort4*>(&out[row * (size_t)D + c]) = o;
    }
}

__global__ __launch_bounds__(256)
void ln_bf16(const float* __restrict__ x, const float* __restrict__ w,
             const float* __restrict__ bias, u16* __restrict__ out, int D)
{
    const size_t row = blockIdx.x;
    const float* xr = x + row * (size_t)D;
    const int c = threadIdx.x * 4;
    float4 v = make_float4(0.f, 0.f, 0.f, 0.f);
    if (c < D) v = *reinterpret_cast<const float4*>(&xr[c]);
    float sum = v.x + v.y + v.z + v.w;
    float sq  = v.x*v.x + v.y*v.y + v.z*v.z + v.w*v.w;
    #pragma unroll
    for (int off = 32; off > 0; off >>= 1) {
        sum += __shfl_down(sum, off);
        sq  += __shfl_down(sq,  off);
    }
    __shared__ float s1[4], s2[4];
    const int wid = threadIdx.x >> 6;
    if ((threadIdx.x & 63) == 0) { s1[wid] = sum; s2[wid] = sq; }
    __syncthreads();
    const float tsum = s1[0] + s1[1] + s1[2] + s1[3];
    const float tsq  = s2[0] + s2[1] + s2[2] + s2[3];
    const float mean = tsum / (float)D;
    const float var  = tsq / (float)D - mean * mean;
    const float rstd = rsqrtf(var + 1e-5f);
    if (c < D) {
        ushort4 o;
        o.x = f2b((v.x - mean) * rstd * w[c+0] + bias[c+0]);
        o.y = f2b((v.y - mean) * rstd * w[c+1] + bias[c+1]);
        o.z = f2b((v.z - mean) * rstd * w[c+2] + bias[c+2]);
        o.w = f2b((v.w - mean) * rstd * w[c+3] + bias[c+3]);
        *reinterpret_cast<ushort4*>(&out[row * (size_t)D + c]) = o;
    }
}

// ---------------- shared 64x64 GEMM core (device, 4 waves) ------------------
__device__ __forceinline__ void gemm64_core(
    const u16* __restrict__ A, const u16* __restrict__ W, void* __restrict__ C,
    int ob, int N, int K, int m0, int n0, u16* As, u16* Ws)
{
    constexpr int PF = 3, LPT = 2, RD = 4;
    const int tid  = threadIdx.x;
    const int lane = tid & 63;
    const int wave = tid >> 6;
    const int wr = wave >> 1, wc = wave & 1;

    const int srow = tid >> 2;
    const int scol = (((tid & 3) ^ ((srow >> 1) & 3))) * 8;
    const u16* Ag = A + (size_t)(m0 + srow) * K + scol;
    const u16* Wg = W + (size_t)(n0 + srow) * K + scol;

    const int fr = lane & 15;
    const int fq = lane >> 4;

    f32x4 acc[2][2] = {};

    auto stage = [&](int buf, int k0) {
        gload16(Ag + k0, &As[buf * 2048 + tid * 8]);
        gload16(Wg + k0, &Ws[buf * 2048 + tid * 8]);
    };
    auto compute = [&](int buf) {
        short8 a[2], b[2];
        #pragma unroll
        for (int m = 0; m < 2; ++m) {
            const int r = wr * 32 + m * 16 + fr;
            a[m] = *reinterpret_cast<const short8*>(&As[buf * 2048 + aswz(r, fq)]);
        }
        #pragma unroll
        for (int n = 0; n < 2; ++n) {
            const int r = wc * 32 + n * 16 + fr;
            b[n] = *reinterpret_cast<const short8*>(&Ws[buf * 2048 + aswz(r, fq)]);
        }
        #pragma unroll
        for (int m = 0; m < 2; ++m)
            #pragma unroll
            for (int n = 0; n < 2; ++n)
                acc[m][n] = __builtin_amdgcn_mfma_f32_16x16x32_bf16(
                    a[m], b[n], acc[m][n], 0, 0, 0);
    };

    const int nt = K / 32;
    #pragma unroll
    for (int i = 0; i < PF; ++i) stage(i, i * 32);

    int cbuf = 0, sbuf = PF;
    for (int t = 0; t <= nt - PF; ++t) {
        asm volatile("s_waitcnt vmcnt(%0)\n\ts_barrier"
                     :: "n"((PF - 1) * LPT) : "memory");
        if (t + PF < nt) {
            stage(sbuf, (t + PF) * 32);
            if (++sbuf == RD) sbuf = 0;
        }
        compute(cbuf);
        if (++cbuf == RD) cbuf = 0;
    }
    #pragma unroll
    for (int i = 1; i < PF; ++i) {
        asm volatile("s_waitcnt vmcnt(%0)\n\ts_barrier"
                     :: "n"((PF - 1 - i) * LPT) : "memory");
        compute(cbuf);
        if (++cbuf == RD) cbuf = 0;
    }

    #pragma unroll
    for (int m = 0; m < 2; ++m)
        #pragma unroll
        for (int j = 0; j < 4; ++j) {
            const size_t row = (size_t)(m0 + wr * 32 + m * 16 + fq * 4 + j);
            #pragma unroll
            for (int n = 0; n < 2; ++n) {
                const size_t idx = row * (size_t)N + (size_t)(n0 + wc * 32 + n * 16 + fr);
                if (ob) ((u16*)C)[idx]  = f2b(acc[m][n][j]);
                else    ((float*)C)[idx] = acc[m][n][j];
            }
        }
}

// -------------- 8-wave 128x128 GEMM core (512 threads, PF=2) ----------------
__device__ __forceinline__ void gemm8_core(
    const u16* __restrict__ A, const u16* __restrict__ W, void* __restrict__ C,
    int ob, int epi, int N, int Kstride, int kcnt, int m0, int n0,
    u16* As, u16* Ws)
{
    constexpr int PF = 2, LPT = 2, RD = 3;
    const int tid  = threadIdx.x;        // 0..511
    const int lane = tid & 63;
    const int wave = tid >> 6;           // 0..7
    const int wr = wave >> 2, wc = wave & 3;

    const int srow = tid >> 2;           // 0..127
    const int scol = (((tid & 3) ^ ((srow >> 1) & 3))) * 8;
    const u16* Ag = A + (size_t)(m0 + srow) * Kstride + scol;
    const u16* Wg = W + (size_t)(n0 + srow) * Kstride + scol;

    const int fr = lane & 15;
    const int fq = lane >> 4;

    f32x4 acc[4][2] = {};

    auto stage = [&](int buf, int k0) {
        gload16(Ag + k0, &As[buf * 4096 + tid * 8]);
        gload16(Wg + k0, &Ws[buf * 4096 + tid * 8]);
    };
    auto compute = [&](int buf) {
        short8 a[4], b[2];
        #pragma unroll
        for (int m = 0; m < 4; ++m) {
            const int r = wr * 64 + m * 16 + fr;
            a[m] = *reinterpret_cast<const short8*>(&As[buf * 4096 + aswz(r, fq)]);
        }
        #pragma unroll
        for (int n = 0; n < 2; ++n) {
            const int r = wc * 32 + n * 16 + fr;
            b[n] = *reinterpret_cast<const short8*>(&Ws[buf * 4096 + aswz(r, fq)]);
        }
        #pragma unroll
        for (int m = 0; m < 4; ++m)
            #pragma unroll
            for (int n = 0; n < 2; ++n)
                acc[m][n] = __builtin_amdgcn_mfma_f32_16x16x32_bf16(
                    a[m], b[n], acc[m][n], 0, 0, 0);
    };

    const int nt = kcnt / 32;
    #pragma unroll
    for (int i = 0; i < PF; ++i) stage(i, i * 32);

    int cbuf = 0, sbuf = PF;
    for (int t = 0; t <= nt - PF; ++t) {
        asm volatile("s_waitcnt vmcnt(%0)\n\ts_barrier"
                     :: "n"((PF - 1) * LPT) : "memory");
        if (t + PF < nt) {
            stage(sbuf, (t + PF) * 32);
            if (++sbuf == RD) sbuf = 0;
        }
        compute(cbuf);
        if (++cbuf == RD) cbuf = 0;
    }
    asm volatile("s_waitcnt vmcnt(0)\n\ts_barrier" ::: "memory");
    compute(cbuf);

    #pragma unroll
    for (int m = 0; m < 4; ++m)
        #pragma unroll
        for (int j = 0; j < 4; ++j) {
            const size_t row = (size_t)(m0 + wr * 64 + m * 16 + fq * 4 + j);
            #pragma unroll
            for (int n = 0; n < 2; ++n) {
                float v = acc[m][n][j];
                if (epi == 1) v = 0.5f * v * (1.f + erff(v * 0.70710678118654752f));
                const size_t idx = row * (size_t)N + (size_t)(n0 + wc * 32 + n * 16 + fr);
                if (ob) ((u16*)C)[idx]  = f2b(v);
                else    ((float*)C)[idx] = v;
            }
        }
}

__global__ __launch_bounds__(512)
void gemm8(const u16* __restrict__ A, const u16* __restrict__ W,
           void* __restrict__ Cv, int N, int K, int ob, int epi, int kchunk)
{
    __shared__ __align__(16) u16 As[3][4096];
    __shared__ __align__(16) u16 Ws[3][4096];
    const int nwg = gridDim.x * gridDim.y;
    const int bid = blockIdx.y * gridDim.x + blockIdx.x;
    const int nid = (bid & 7) * (nwg >> 3) + (bid >> 3);
    const int by  = nid % gridDim.y;
    const int bx  = nid / gridDim.y;
    const int kz  = blockIdx.z * kchunk;
    void* C = ob ? Cv : (void*)((float*)Cv + (size_t)blockIdx.z * M_ROWS * N);
    gemm8_core(A + kz, W + kz, C, ob, epi, N, K, kchunk,
               by * 128, bx * 128, &As[0][0], &Ws[0][0]);
}

struct GemmPack4 { const u16* A[4]; const u16* W[4]; u16* C[4]; int N[4]; };

__global__ __launch_bounds__(512)
void gemm8_bat4(GemmPack4 p)
{
    __shared__ __align__(16) u16 As[3][4096];
    __shared__ __align__(16) u16 Ws[3][4096];
    constexpr int pre[5] = {0, 192, 256, 384, 576};
    const int nwg = gridDim.x * gridDim.y;           // 576
    const int bid = blockIdx.y * gridDim.x + blockIdx.x;
    const int nid = (bid & 7) * (nwg >> 3) + (bid >> 3);
    int seg = 0;
    #pragma unroll
    for (int i = 1; i < 4; ++i) seg += (nid >= pre[i]);
    const int idx = nid - pre[seg];
    const int nx  = p.N[seg] >> 7;
    const int bx  = idx % nx;
    const int by  = idx / nx;
    gemm8_core(p.A[seg], p.W[seg], p.C[seg], 1, 0, p.N[seg], 1024, 1024,
               by * 128, bx * 128, &As[0][0], &Ws[0][0]);
}

// ------------------------------ MFMA GEMM ----------------------------------
template<int BM, int BN, int EPI, int OB>
__global__ __launch_bounds__(256)
void gemm_mfma(const u16* __restrict__ A, const u16* __restrict__ W,
               void* __restrict__ Cv, int N, int K,
               const float* __restrict__ gatep, int kchunk)
{
    constexpr int MF  = BM / 32;
    constexpr int NF  = BN / 32;
    constexpr int LPT = BM / 64 + BN / 64;
    constexpr int PF  = 3;
    constexpr int RD  = 4;
    __shared__ __align__(16) u16 As[RD][BM * 32];
    __shared__ __align__(16) u16 Ws[RD][BN * 32];
    const int tid  = threadIdx.x;
    const int lane = tid & 63;
    const int wave = tid >> 6;
    const int wr = wave >> 1, wc = wave & 1;

    const int nwg = gridDim.x * gridDim.y;
    const int bid = blockIdx.y * gridDim.x + blockIdx.x;
    const int nid = (bid & 7) * (nwg >> 3) + (bid >> 3);
    const int by  = nid % gridDim.y;
    const int bx  = nid / gridDim.y;
    const int m0 = by * BM, n0 = bx * BN;
    const int kz = blockIdx.z * kchunk;

    const int srow = tid >> 2;
    const int scol = (((tid & 3) ^ ((srow >> 1) & 3))) * 8;
    const u16* Ag = A + (size_t)(m0 + srow) * K + scol + kz;
    const u16* Wg = W + (size_t)(n0 + srow) * K + scol + kz;

    const int fr = lane & 15;
    const int fq = lane >> 4;

    f32x4 acc[MF][NF] = {};

    auto stage = [&](int buf, int k0) {
        #pragma unroll
        for (int i = 0; i < BM / 64; ++i)
            gload16(Ag + k0 + (size_t)(i * 64) * K, &As[buf][tid * 8 + i * 2048]);
        #pragma unroll
        for (int i = 0; i < BN / 64; ++i)
            gload16(Wg + k0 + (size_t)(i * 64) * K, &Ws[buf][tid * 8 + i * 2048]);
    };
    auto compute = [&](int buf) {
        short8 a[MF], b[NF];
        #pragma unroll
        for (int m = 0; m < MF; ++m) {
            const int r = wr * (BM / 2) + m * 16 + fr;
            a[m] = *reinterpret_cast<const short8*>(&As[buf][aswz(r, fq)]);
        }
        #pragma unroll
        for (int n = 0; n < NF; ++n) {
            const int r = wc * (BN / 2) + n * 16 + fr;
            b[n] = *reinterpret_cast<const short8*>(&Ws[buf][aswz(r, fq)]);
        }
        #pragma unroll
        for (int m = 0; m < MF; ++m)
            #pragma unroll
            for (int n = 0; n < NF; ++n)
                acc[m][n] = __builtin_amdgcn_mfma_f32_16x16x32_bf16(
                    a[m], b[n], acc[m][n], 0, 0, 0);
    };

    const int nt = kchunk / 32;
    #pragma unroll
    for (int i = 0; i < PF; ++i) stage(i, i * 32);

    int cbuf = 0, sbuf = PF;
    for (int t = 0; t <= nt - PF; ++t) {
        asm volatile("s_waitcnt vmcnt(%0)\n\ts_barrier"
                     :: "n"((PF - 1) * LPT) : "memory");
        if (t + PF < nt) {
            stage(sbuf, (t + PF) * 32);
            if (++sbuf == RD) sbuf = 0;
        }
        compute(cbuf);
        if (++cbuf == RD) cbuf = 0;
    }
    #pragma unroll
    for (int i = 1; i < PF; ++i) {
        asm volatile("s_waitcnt vmcnt(%0)\n\ts_barrier"
                     :: "n"((PF - 1 - i) * LPT) : "memory");
        compute(cbuf);
        if (++cbuf == RD) cbuf = 0;
    }

    float* Cz = (float*)Cv + (size_t)blockIdx.z * M_ROWS * N;
    const float gate = (EPI == 2) ? gatep[0] : 0.f;
    #pragma unroll
    for (int m = 0; m < MF; ++m) {
        #pragma unroll
        for (int j = 0; j < 4; ++j) {
            const size_t row = (size_t)(m0 + wr * (BM / 2) + m * 16 + fq * 4 + j);
            #pragma unroll
            for (int n = 0; n < NF; ++n) {
                float v = acc[m][n][j];
                const size_t idx = row * (size_t)N + (size_t)(n0 + wc * (BN / 2) + n * 16 + fr);
                if (EPI == 1) v = 0.5f * v * (1.f + erff(v * 0.70710678118654752f));
                if (OB) {
                    ((u16*)Cv)[idx] = f2b(v);
                } else {
                    if (EPI == 2) Cz[idx] = Cz[idx] + gate * v;
                    else          Cz[idx] = v;
                }
            }
        }
    }
}

// -------- batched gate-path GEMMs: wt_out + gq + gk + gv (K=512) ------------
struct GemmPack4b { const u16* A[4]; const u16* W[4]; void* C[4]; int N[4]; int ob[4]; };

__global__ __launch_bounds__(256)
void gemm_bat4b(GemmPack4b p)
{
    __shared__ __align__(16) u16 As[4][2048];
    __shared__ __align__(16) u16 Ws[4][2048];
    constexpr int pre[5] = {0, 512, 768, 1024, 1280};
    const int nwg = gridDim.x * gridDim.y;           // 1280
    const int bid = blockIdx.y * gridDim.x + blockIdx.x;
    const int nid = (bid & 7) * (nwg >> 3) + (bid >> 3);
    int seg = 0;
    #pragma unroll
    for (int i = 1; i < 4; ++i) seg += (nid >= pre[i]);
    const int idx = nid - pre[seg];
    const int nx  = p.N[seg] >> 6;
    const int bx  = idx % nx;
    const int by  = idx / nx;
    gemm64_core(p.A[seg], p.W[seg], p.C[seg], p.ob[seg], p.N[seg], 512,
                by * 64, bx * 64, &As[0][0], &Ws[0][0]);
}

// ---------------- split-K reduce: C += gate * (p0+p1+p2+p3) ----------------
__global__ __launch_bounds__(256)
void redk(const float* __restrict__ p, const float* __restrict__ gatep,
          float* __restrict__ C)
{
    const int i = (blockIdx.x * 256 + threadIdx.x) * 4;
    const float g = gatep[0];
    const float4 a = *reinterpret_cast<const float4*>(p + i);
    const float4 b = *reinterpret_cast<const float4*>(p + 2097152 + i);
    const float4 c = *reinterpret_cast<const float4*>(p + 4194304 + i);
    const float4 d = *reinterpret_cast<const float4*>(p + 6291456 + i);
    float4 o = *reinterpret_cast<float4*>(C + i);
    o.x += g * ((a.x + b.x) + (c.x + d.x));
    o.y += g * ((a.y + b.y) + (c.y + d.y));
    o.z += g * ((a.z + b.z) + (c.z + d.z));
    o.w += g * ((a.w + b.w) + (c.w + d.w));
    *reinterpret_cast<float4*>(C + i) = o;
}

// ------------------------- MFMA fused attention ----------------------------
// Batched, problem index in fast bits. LDS half-major + aswz (min-cycle).
// exp2-domain softmax with defer-max (T13); scale folded into the MAX and the
// exp2 fma (1 mul/iter instead of 16); s_setprio around MFMA.
struct AttnPack {
    const u16* Q[3]; const u16* K[3]; const u16* V[3]; void* O[3];
    int qs[3], ks[3], vs[3], os[3], ob[3];
};

__global__ __launch_bounds__(256)
void attn_mfma(AttnPack p, int NP)
{
    const int nwg = gridDim.x * gridDim.y;
    const int bid = blockIdx.y * gridDim.x + blockIdx.x;
    const int nid = (bid & 7) * (nwg >> 3) + (bid >> 3);
    const int z  = nid % NP;
    const int r_ = nid / NP;                 // [0,256)
    const int qt = r_ & 15;
    const int bh = r_ >> 4;

    const u16* __restrict__ Q = p.Q[z];
    const u16* __restrict__ K = p.K[z];
    const u16* __restrict__ V = p.V[z];
    void* __restrict__ Ov = p.O[z];
    const int qs = p.qs[z], ks = p.ks[z], vs = p.vs[z], os = p.os[z];
    const int ob = p.ob[z];

    __shared__ __align__(16) u16 Ks[2][128 * 32];  // [half*64+kv][32]
    __shared__ __align__(16) u16 Vt[2][128 * 32];  // [half*64+d][32]
    __shared__ __align__(16) u16 Ps[4][32 * 32];   // per-wave [half*16+q][32]
    const int tid  = threadIdx.x;
    const int lane = tid & 63;
    const int wave = tid >> 6;
    const int fr = lane & 15;
    const int fq = lane >> 4;

    const int b   = bh >> 3;
    const int hc  = (bh & 7) * 64;
    const size_t qrow0 = (size_t)b * SEQ + (size_t)qt * 64;
    const size_t krow0 = (size_t)b * SEQ;

    const float SC = 0.125f * 1.44269504088896f;   // scale * log2(e)

    short8 qf[2];
    {
        const u16* qp = Q + (qrow0 + wave * 16 + fr) * qs + hc + fq * 8;
        qf[0] = *reinterpret_cast<const short8*>(qp);
        qf[1] = *reinterpret_cast<const short8*>(qp + 32);
    }

    const int skr = tid >> 2;
    const int skc = (tid & 3) * 16;
    const int svk = (tid >> 4) * 4;
    const int svd = (tid & 15) * 4;

    const int kprow = (skc >= 32 ? 64 : 0) + skr;
    const int kc0   = (skc & 31) >> 3;
    const int vbase  = (svk >= 32) ? 64 : 0;
    const int vchunk = (svk & 31) >> 3;
    const int vpos   = svk & 7;

    short8 kreg0, kreg1;
    ushort4 vr0, vr1, vr2, vr3;
    auto load_tile = [&](int kt) {
        const u16* kp = K + (krow0 + kt * 64 + skr) * ks + hc + skc;
        kreg0 = *reinterpret_cast<const short8*>(kp);
        kreg1 = *reinterpret_cast<const short8*>(kp + 8);
        const u16* vp = V + (krow0 + kt * 64 + svk) * vs + hc + svd;
        vr0 = *reinterpret_cast<const ushort4*>(vp);
        vr1 = *reinterpret_cast<const ushort4*>(vp + vs);
        vr2 = *reinterpret_cast<const ushort4*>(vp + 2 * (size_t)vs);
        vr3 = *reinterpret_cast<const ushort4*>(vp + 3 * (size_t)vs);
    };
    auto write_tile = [&](int bf) {
        *reinterpret_cast<short8*>(&Ks[bf][aswz(kprow, kc0)])     = kreg0;
        *reinterpret_cast<short8*>(&Ks[bf][aswz(kprow, kc0 + 1)]) = kreg1;
        uint2 w;
        #pragma unroll
        for (int i = 0; i < 4; ++i) {
            u16* dst = &Vt[bf][aswz(vbase + svd + i, vchunk) + vpos];
            unsigned lo, hi;
            if (i == 0) { lo = (unsigned)vr0.x | ((unsigned)vr1.x << 16);
                          hi = (unsigned)vr2.x | ((unsigned)vr3.x << 16); }
            else if (i == 1) { lo = (unsigned)vr0.y | ((unsigned)vr1.y << 16);
                               hi = (unsigned)vr2.y | ((unsigned)vr3.y << 16); }
            else if (i == 2) { lo = (unsigned)vr0.z | ((unsigned)vr1.z << 16);
                               hi = (unsigned)vr2.z | ((unsigned)vr3.z << 16); }
            else { lo = (unsigned)vr0.w | ((unsigned)vr1.w << 16);
                   hi = (unsigned)vr2.w | ((unsigned)vr3.w << 16); }
            w.x = lo; w.y = hi;
            *reinterpret_cast<uint2*>(dst) = w;
        }
    };

    float m_run = -1e30f, l_run = 0.f;     // exp2-scaled domain
    f32x4 acc[4] = {};

    load_tile(0);
    write_tile(0);
    __syncthreads();

    constexpr int NT = SEQ / 64;
    for (int kt = 0; kt < NT; ++kt) {
        const int bf = kt & 1;
        if (kt + 1 < NT) load_tile(kt + 1);

        f32x4 st[4] = {};
        __builtin_amdgcn_s_setprio(1);
        #pragma unroll
        for (int kn = 0; kn < 4; ++kn) {
            const int r = kn * 16 + fr;
            const short8 ka0 = *reinterpret_cast<const short8*>(
                &Ks[bf][aswz(r, fq)]);
            const short8 ka1 = *reinterpret_cast<const short8*>(
                &Ks[bf][aswz(64 + r, fq)]);
            st[kn] = __builtin_amdgcn_mfma_f32_16x16x32_bf16(ka0, qf[0], st[kn], 0, 0, 0);
            st[kn] = __builtin_amdgcn_mfma_f32_16x16x32_bf16(ka1, qf[1], st[kn], 0, 0, 0);
        }
        __builtin_amdgcn_s_setprio(0);

        // max over RAW S, scale once (SC > 0 so order-preserving)
        float mxr = -1e30f;
        #pragma unroll
        for (int kn = 0; kn < 4; ++kn)
            #pragma unroll
            for (int r = 0; r < 4; ++r)
                mxr = fmaxf(mxr, st[kn][r]);
        mxr = fmaxf(mxr, __shfl_xor(mxr, 16, 64));
        mxr = fmaxf(mxr, __shfl_xor(mxr, 32, 64));
        const float mx = mxr * SC;             // exp2-scaled domain

        // defer-max (T13): keep old max if growth <= 8 (P bounded by 2^8).
        const bool noresc = __all(mx <= m_run + 8.f);
        const float mold = m_run;
        const float mnew = noresc ? m_run : fmaxf(m_run, mx);
        m_run = mnew;

        float psum = 0.f;
        #pragma unroll
        for (int kn = 0; kn < 4; ++kn) {
            const float p0 = exp2f(fmaf(st[kn][0], SC, -mnew));
            const float p1 = exp2f(fmaf(st[kn][1], SC, -mnew));
            const float p2 = exp2f(fmaf(st[kn][2], SC, -mnew));
            const float p3 = exp2f(fmaf(st[kn][3], SC, -mnew));
            psum += (p0 + p1) + (p2 + p3);
            uint2 w;
            w.x = cvtpk_bf16(p0, p1);
            w.y = cvtpk_bf16(p2, p3);
            const int prow = (kn >> 1) * 16 + fr;
            const int pcol = (kn & 1) * 16 + fq * 4;
            *reinterpret_cast<uint2*>(
                &Ps[wave][aswz(prow, pcol >> 3) + (pcol & 7)]) = w;
        }
        psum += __shfl_xor(psum, 16, 64);
        psum += __shfl_xor(psum, 32, 64);

        if (noresc) {
            l_run += psum;
        } else {
            const float corr = exp2f(mold - mnew);
            l_run = l_run * corr + psum;
            float cq[4];
            #pragma unroll
            for (int j = 0; j < 4; ++j) cq[j] = __shfl(corr, fq * 4 + j, 64);
            #pragma unroll
            for (int nd = 0; nd < 4; ++nd)
                #pragma unroll
                for (int j = 0; j < 4; ++j)
                    acc[nd][j] *= cq[j];
        }

        short8 pa0 = *reinterpret_cast<const short8*>(&Ps[wave][aswz(fr, fq)]);
        short8 pa1 = *reinterpret_cast<const short8*>(&Ps[wave][aswz(16 + fr, fq)]);
        __builtin_amdgcn_s_setprio(1);
        #pragma unroll
        for (int nd = 0; nd < 4; ++nd) {
            const int d = nd * 16 + fr;
            const short8 vb0 = *reinterpret_cast<const short8*>(
                &Vt[bf][aswz(d, fq)]);
            const short8 vb1 = *reinterpret_cast<const short8*>(
                &Vt[bf][aswz(64 + d, fq)]);
            acc[nd] = __builtin_amdgcn_mfma_f32_16x16x32_bf16(pa0, vb0, acc[nd], 0, 0, 0);
            acc[nd] = __builtin_amdgcn_mfma_f32_16x16x32_bf16(pa1, vb1, acc[nd], 0, 0, 0);
        }
        __builtin_amdgcn_s_setprio(0);

        if (kt + 1 < NT) write_tile(bf ^ 1);
        __syncthreads();
    }

    float iq[4];
    #pragma unroll
    for (int j = 0; j < 4; ++j) iq[j] = 1.f / __shfl(l_run, fq * 4 + j, 64);
    #pragma unroll
    for (int j = 0; j < 4; ++j) {
        const size_t orow = (qrow0 + wave * 16 + fq * 4 + j) * os + hc;
        #pragma unroll
        for (int nd = 0; nd < 4; ++nd) {
            const float v = acc[nd][j] * iq[j];
            if (ob) ((u16*)Ov)[orow + nd * 16 + fr] = f2b(v);
            else    ((float*)Ov)[orow + nd * 16 + fr] = v;
        }
    }
}

// -------------------- gate mix (dot, softmax-2, blend) ---------------------
__global__ __launch_bounds__(256)
void mix_kernel(const float* __restrict__ gctx, const float* __restrict__ mixw,
                const float* __restrict__ mixb, const float* __restrict__ so,
                const float* __restrict__ co, u16* __restrict__ mixed)
{
    const size_t row = blockIdx.x;
    const float* g = gctx + row * 512;
    float d0 = 0.f, d1 = 0.f;
    for (int c = threadIdx.x; c < 512; c += 256) {
        const float gv = g[c];
        d0 = fmaf(gv, mixw[c], d0);
        d1 = fmaf(gv, mixw[512 + c], d1);
    }
    #pragma unroll
    for (int off = 32; off > 0; off >>= 1) {
        d0 += __shfl_down(d0, off);
        d1 += __shfl_down(d1, off);
    }
    __shared__ float sA[4], sB[4];
    const int wid = threadIdx.x >> 6;
    if ((threadIdx.x & 63) == 0) { sA[wid] = d0; sB[wid] = d1; }
    __syncthreads();
    const float t0 = sA[0] + sA[1] + sA[2] + sA[3] + mixb[0];
    const float t1 = sB[0] + sB[1] + sB[2] + sB[3] + mixb[1];
    const float mx = fmaxf(t0, t1);
    const float e0 = __expf(t0 - mx), e1 = __expf(t1 - mx);
    const float inv = 1.f / (e0 + e1);
    const float w0 = e0 * inv, w1 = e1 * inv;
    for (int c = threadIdx.x; c < 512; c += 256)
        mixed[row * 512 + c] = f2b(w0 * so[row * 512 + c] + w1 * co[row * 512 + c]);
}

// ---------------------------------------------------------------------------
extern "C" void kernel_launch(void* const* d_in, const int* in_sizes, int n_in,
                              void* d_out, int out_size, void* d_ws, size_t ws_size,
                              hipStream_t stream)
{
    const float* query     = (const float*)d_in[0];
    const float* kvwt      = (const float*)d_in[1];
    const float* nq_w      = (const float*)d_in[2];
    const float* nq_b      = (const float*)d_in[3];
    const float* nkv_w     = (const float*)d_in[4];
    const float* nkv_b     = (const float*)d_in[5];
    const float* wq_cross  = (const float*)d_in[6];
    const float* wkv_cross = (const float*)d_in[7];
    const float* wqkv_self = (const float*)d_in[8];
    const float* gn_w      = (const float*)d_in[9];
    const float* gn_b      = (const float*)d_in[10];
    const float* mha_in_w  = (const float*)d_in[11];
    const float* mha_out_w = (const float*)d_in[12];
    const float* mix_w     = (const float*)d_in[13];
    const float* mix_b     = (const float*)d_in[14];
    const float* w_out     = (const float*)d_in[15];
    const float* ff_ln_w   = (const float*)d_in[16];
    const float* ff_ln_b   = (const float*)d_in[17];
    const float* ff_fc1    = (const float*)d_in[18];
    const float* ff_fc2    = (const float*)d_in[19];
    const float* ff_gate   = (const float*)d_in[20];

    float* delta_out = (float*)d_out;                          // stack[0]
    float* wt_out    = (float*)d_out + (size_t)M_ROWS * 1024;  // stack[1]

    // ---- workspace layout (byte offsets; high-water 68,157,440 B) ----
    char* wsb = (char*)d_ws;
    u16*   qkv_b   = (u16*)  (wsb + 0);
    u16*   kv_c_b  = (u16*)  (wsb + 6291456);
    u16*   q_c_b   = (u16*)  (wsb + 10485760);
    float* cross_f = (float*)(wsb + 12582912);
    float* self_f  = (float*)(wsb + 16777216);
    u16*   kvn_b   = (u16*)  (wsb + 20971520);
    u16*   qn_b    = (u16*)  (wsb + 25165824);
    u16*   wta_b   = (u16*)  (wsb + 29360128);
    u16*   con_b   = (u16*)  (wsb + 31457280);
    u16*   gq_b    = qkv_b;
    u16*   gk_b    = qkv_b + 1048576;
    u16*   gv_b    = qkv_b + 2097152;
    float* gctx_f  = (float*)kv_c_b;
    u16*   gattn_b = kvn_b;
    u16*   mixed_b = kvn_b + 1048576;
    u16*   lnd_b   = qn_b;
    u16*   ffh_b   = qkv_b;
    float* part_f  = (float*)(wsb + 16777216);
    u16*   qkv_s_b = (u16*)  (wsb + 59768832);
    u16*   son_b   = (u16*)  (wsb + 66060288);
    u16* wqkv_self_b = (u16*)(wsb + 33554432);
    u16* wq_cross_b  = (u16*)(wsb + 36700160);
    u16* wkv_cross_b = (u16*)(wsb + 37748736);
    u16* mha_in_b    = (u16*)(wsb + 39845888);
    u16* mha_out_b   = (u16*)(wsb + 41418752);
    u16* w_out_b     = (u16*)(wsb + 41943040);
    u16* ff_fc1_b    = (u16*)(wsb + 42991616);
    u16* ff_fc2_b    = (u16*)(wsb + 51380224);

    const dim3 blk(256);
    const dim3 blk8(512);

    // 0. fused weight conversion
    CvtPack cp;
    cp.s[0] = wqkv_self; cp.d[0] = wqkv_self_b;
    cp.s[1] = wq_cross;  cp.d[1] = wq_cross_b;
    cp.s[2] = wkv_cross; cp.d[2] = wkv_cross_b;
    cp.s[3] = mha_in_w;  cp.d[3] = mha_in_b;
    cp.s[4] = mha_out_w; cp.d[4] = mha_out_b;
    cp.s[5] = w_out;     cp.d[5] = w_out_b;
    cp.s[6] = ff_fc1;    cp.d[6] = ff_fc1_b;
    cp.s[7] = ff_fc2;    cp.d[7] = ff_fc2_b;
    cvt8_kernel<<<dim3(12800), blk, 0, stream>>>(cp);

    // 1+5. kvn = LN(kv_feats_wt), qn = LN(query)
    ln_dual<<<dim3(2 * M_ROWS), blk, 0, stream>>>(
        kvwt, nkv_w, nkv_b, kvn_b, query, nq_w, nq_b, qn_b, 1024);

    // 2,6,7,9: four projection GEMMs, 8-wave 128x128 (grid 576)
    GemmPack4 g4;
    g4.A[0] = kvn_b; g4.W[0] = wqkv_self_b; g4.C[0] = qkv_b;   g4.N[0] = 1536;
    g4.A[1] = qn_b;  g4.W[1] = wq_cross_b;  g4.C[1] = q_c_b;   g4.N[1] = 512;
    g4.A[2] = kvn_b; g4.W[2] = wkv_cross_b; g4.C[2] = kv_c_b;  g4.N[2] = 1024;
    g4.A[3] = qn_b;  g4.W[3] = wqkv_self_b; g4.C[3] = qkv_s_b; g4.N[3] = 1536;
    gemm8_bat4<<<dim3(18, 32), blk8, 0, stream>>>(g4);

    // 3,8,10: three attentions, problem index in fast bits (grid 48x16)
    AttnPack ap;
    ap.Q[0] = qkv_b;    ap.K[0] = qkv_b + 512;    ap.V[0] = qkv_b + 1024;    ap.O[0] = wta_b;
    ap.qs[0] = 1536; ap.ks[0] = 1536; ap.vs[0] = 1536; ap.os[0] = 512; ap.ob[0] = 1;
    ap.Q[1] = q_c_b;    ap.K[1] = kv_c_b;         ap.V[1] = kv_c_b + 512;    ap.O[1] = cross_f;
    ap.qs[1] = 512;  ap.ks[1] = 1024; ap.vs[1] = 1024; ap.os[1] = 512; ap.ob[1] = 0;
    ap.Q[2] = qkv_s_b;  ap.K[2] = qkv_s_b + 512;  ap.V[2] = qkv_s_b + 1024;  ap.O[2] = self_f;
    ap.qs[2] = 1536; ap.ks[2] = 1536; ap.vs[2] = 1536; ap.os[2] = 512; ap.ob[2] = 0;
    attn_mfma<<<dim3(48, 16), blk, 0, stream>>>(ap, 3);

    // 11. son = LN(self; gn), con = LN(cross; gn)
    ln_dual<<<dim3(2 * M_ROWS), blk, 0, stream>>>(
        self_f, gn_w, gn_b, son_b, cross_f, gn_w, gn_b, con_b, 512);

    // 4+12. wt_out + gq/gk/gv in ONE batched launch (grid 1280, K=512)
    GemmPack4b g4b;
    g4b.A[0] = wta_b; g4b.W[0] = w_out_b;             g4b.C[0] = wt_out; g4b.N[0] = 1024; g4b.ob[0] = 0;
    g4b.A[1] = son_b; g4b.W[1] = mha_in_b;            g4b.C[1] = gq_b;   g4b.N[1] = 512;  g4b.ob[1] = 1;
    g4b.A[2] = con_b; g4b.W[2] = mha_in_b + 512*512;  g4b.C[2] = gk_b;   g4b.N[2] = 512;  g4b.ob[2] = 1;
    g4b.A[3] = con_b; g4b.W[3] = mha_in_b + 1024*512; g4b.C[3] = gv_b;   g4b.N[3] = 512;  g4b.ob[3] = 1;
    gemm_bat4b<<<dim3(40, 32), blk, 0, stream>>>(g4b);

    // 13. gate attention (single problem)
    AttnPack gp;
    gp.Q[0] = gq_b; gp.K[0] = gk_b; gp.V[0] = gv_b; gp.O[0] = gattn_b;
    gp.qs[0] = 512; gp.ks[0] = 512; gp.vs[0] = 512; gp.os[0] = 512; gp.ob[0] = 1;
    gp.Q[1] = gp.Q[0]; gp.K[1] = gp.K[0]; gp.V[1] = gp.V[0]; gp.O[1] = gp.O[0];
    gp.qs[1] = 512; gp.ks[1] = 512; gp.vs[1] = 512; gp.os[1] = 512; gp.ob[1] = 1;
    gp.Q[2] = gp.Q[0]; gp.K[2] = gp.K[0]; gp.V[2] = gp.V[0]; gp.O[2] = gp.O[0];
    gp.qs[2] = 512; gp.ks[2] = 512; gp.vs[2] = 512; gp.os[2] = 512; gp.ob[2] = 1;
    attn_mfma<<<dim3(16, 16), blk, 0, stream>>>(gp, 1);
    // 14. gate_ctx = gate_attn @ mha_out_w^T (f32 out)
    gemm_mfma<64,64,0,0><<<dim3(8, 32), blk, 0, stream>>>(gattn_b, mha_out_b, gctx_f, 512, 512, nullptr, 512);
    // 15. mixed = softmax-gate blend (bf16 out)
    mix_kernel<<<dim3(M_ROWS), blk, 0, stream>>>(gctx_f, mix_w, mix_b, self_f, cross_f, mixed_b);
    // 16. delta = mixed @ w_out^T -> stack[0] (f32)  64^2 grid 512
    gemm_mfma<64,64,0,0><<<dim3(16, 32), blk, 0, stream>>>(mixed_b, w_out_b, delta_out, 1024, 512, nullptr, 512);
    // 17. ln_delta = LN(delta; ff_ln)
    ln_bf16<<<dim3(M_ROWS), blk, 0, stream>>>(delta_out, ff_ln_w, ff_ln_b, lnd_b, 1024);
    // 18. ffh = gelu(ln_delta @ ff_fc1^T)   8-wave 128x128 PF=2, grid (32,16)
    gemm8<<<dim3(32, 16), blk8, 0, stream>>>(lnd_b, ff_fc1_b, ffh_b, 4096, 1024, 1, 1, 1024);
    // 19a. fc2 split-K=4 partials           8-wave 128x128 PF=2, grid (8,16,4)
    gemm8<<<dim3(8, 16, 4), blk8, 0, stream>>>(ffh_b, ff_fc2_b, part_f, 1024, 4096, 0, 0, 1024);
    // 19b. delta += gate * sum(partials)
    redk<<<dim3(2048), blk, 0, stream>>>(part_f, ff_gate, delta_out);
}